// Round 17
// baseline (3268.444 us; speedup 1.0000x reference)
//
#include <hip/hip_runtime.h>
#include <hip/hip_bf16.h>

#define BB 8
#define CC 16
#define HH 128
#define WW 128
#define HD 64
#define WD 64
#define LP 4096
#define K1 144
#define N2 256

// Read input element idx as float, honoring detected storage dtype.
__device__ __forceinline__ float ld_in(const void* p, long idx, int bf) {
    if (bf) {
        unsigned short u = ((const unsigned short*)p)[idx];
        return __uint_as_float(((unsigned int)u) << 16);
    }
    return ((const float*)p)[idx];
}

// ---------------------------------------------------------------------------
// storage dtype detect (robustness; inputs are expected fp32)
// ---------------------------------------------------------------------------
__global__ void detect_kernel(const unsigned int* __restrict__ w, int* __restrict__ flag) {
    if (threadIdx.x == 0) {
        int cnt = 0;
        for (int i = 0; i < 256; i++) {
            unsigned int e = (w[i] >> 7) & 0xFF;
            if (e >= 100 && e <= 140) cnt++;
        }
        *flag = (cnt >= 192) ? 1 : 0;
    }
}

// ---------------------------------------------------------------------------
// prep: Fgp[b,l,k] fp32; Kcols[b,l,k] = bg/norm, norm = sqrt(sum bg^2)
// clamped at 1e-4; mmg[b,l] = mm. One block per (b,l).
// ---------------------------------------------------------------------------
__global__ __launch_bounds__(256) void prep_kernel(
    const void* __restrict__ fg, const void* __restrict__ bg,
    const void* __restrict__ mask, const int* __restrict__ flagp,
    float* __restrict__ Fgp, float* __restrict__ Kcols, float* __restrict__ mmg)
{
    int bf = *flagp;
    int bl = blockIdx.x;
    int b = bl >> 12, l = bl & 4095;
    int py = l >> 6, px = l & 63;
    int tid = threadIdx.x;
    __shared__ float sq[160];
    __shared__ float nrm_sh;

    float fgv = 0.f, bgv = 0.f;
    if (tid < K1) {
        int c = tid / 9;
        int r9 = tid - c * 9;
        int ky = r9 / 3, kx = r9 - ky * 3;
        int yy = py + ky - 1, xx = px + kx - 1;
        if (yy >= 0 && yy < HD && xx >= 0 && xx < WD) {
            long base = ((long)(b * CC + c) * HH + 2 * yy) * WW + 2 * xx;
            fgv = ld_in(fg, base, bf);
            bgv = ld_in(bg, base, bf);
        }
        sq[tid] = bgv * bgv;
    }
    __syncthreads();
    if (tid == 0) {
        float S = 0.f;
        for (int k = 0; k < K1; k++) S += sq[k];
        nrm_sh = fmaxf(sqrtf(S), 1e-4f);
    }
    __syncthreads();
    float nrm = nrm_sh;

    if (tid < K1) {
        long base = (long)bl * K1 + tid;
        Fgp[base] = fgv;
        Kcols[base] = bgv / nrm;
    }
    if (tid == 0) {
        float s9 = 0.f;
        for (int ky = 0; ky < 3; ky++)
            for (int kx = 0; kx < 3; kx++) {
                int yy = py + ky - 1, xx = px + kx - 1;
                if (yy >= 0 && yy < HD && xx >= 0 && xx < WD)
                    s9 += ld_in(mask, ((long)b * HH + 2 * yy) * WW + 2 * xx, bf);
            }
        mmg[bl] = (s9 == 0.0f) ? 1.0f : 0.0f;
    }
}

// ---------------------------------------------------------------------------
// bgcols: Bgcols[b,l,j], j=(c,dy,dx): 4x4 full-res bg patches (stride 2, pad 1)
// ---------------------------------------------------------------------------
__global__ __launch_bounds__(256) void bgcols_kernel(
    const void* __restrict__ bg, const int* __restrict__ flagp,
    float* __restrict__ Bgcols)
{
    int bl = blockIdx.x;
    int bf = *flagp;
    int b = bl >> 12, l = bl & 4095;
    int py = l >> 6, px = l & 63;
    int j = threadIdx.x;
    int c = j >> 4, dy = (j >> 2) & 3, dx = j & 3;
    int Y = 2 * py + dy - 1, X = 2 * px + dx - 1;
    float v = 0.f;
    if (Y >= 0 && Y < HH && X >= 0 && X < WW)
        v = ld_in(bg, ((long)(b * CC + c) * HH + Y) * WW + X, bf);
    Bgcols[(long)bl * N2 + j] = v;
}

// ---------------------------------------------------------------------------
// gemmZ (NT): Z[p,l] = mm[l] ? 10 * dot144(Fgp[p], Kcols[l]) : 0
// (shown-code semantics: masked keys keep z=0 and stay in the softmax denom)
// ---------------------------------------------------------------------------
__global__ __launch_bounds__(256) void gemmZ_kernel(
    const float* __restrict__ A, const float* __restrict__ Bm,
    const float* __restrict__ mmv, float* __restrict__ Z)
{
    __shared__ float As[64][17];
    __shared__ float Bs[64][17];

    int t = threadIdx.x;
    int l0 = blockIdx.x * 64, p0 = blockIdx.y * 64;
    int lr = t >> 2, kq = (t & 3) * 4;
    int tx = t & 15, ty = t >> 4;

    float acc[4][4] = {};

    for (int kt = 0; kt < K1; kt += 16) {
        float4 av = *(const float4*)&A[(long)(p0 + lr) * K1 + kt + kq];
        float4 bv = *(const float4*)&Bm[(long)(l0 + lr) * K1 + kt + kq];
        As[lr][kq + 0] = av.x; As[lr][kq + 1] = av.y; As[lr][kq + 2] = av.z; As[lr][kq + 3] = av.w;
        Bs[lr][kq + 0] = bv.x; Bs[lr][kq + 1] = bv.y; Bs[lr][kq + 2] = bv.z; Bs[lr][kq + 3] = bv.w;
        __syncthreads();
#pragma unroll
        for (int kk = 0; kk < 16; kk++) {
            float a[4], bb[4];
#pragma unroll
            for (int i = 0; i < 4; i++) a[i] = As[ty * 4 + i][kk];
#pragma unroll
            for (int j = 0; j < 4; j++) bb[j] = Bs[tx * 4 + j][kk];
#pragma unroll
            for (int i = 0; i < 4; i++)
#pragma unroll
                for (int j = 0; j < 4; j++) acc[i][j] += a[i] * bb[j];
        }
        __syncthreads();
    }

    float mj[4];
#pragma unroll
    for (int j = 0; j < 4; j++) mj[j] = mmv[l0 + tx * 4 + j];
#pragma unroll
    for (int i = 0; i < 4; i++) {
        float z[4];
#pragma unroll
        for (int j = 0; j < 4; j++)
            z[j] = (mj[j] > 0.f) ? 10.0f * acc[i][j] : 0.f;
        *(float4*)&Z[(long)(p0 + ty * 4 + i) * LP + l0 + tx * 4] =
            make_float4(z[0], z[1], z[2], z[3]);
    }
}

// ---------------------------------------------------------------------------
// stats per p-row: m = max_l Z (masked z=0 included); denom = sum_l exp(Z-m)
// ---------------------------------------------------------------------------
__global__ __launch_bounds__(256) void stats_kernel(
    const float* __restrict__ Z, float* __restrict__ m_out, float* __restrict__ d_out)
{
    int p = blockIdx.x;
    int t = threadIdx.x;
    const float4* Z4 = (const float4*)(Z + (long)p * LP);
    float4 v[4];
    float mx = -1e30f;
#pragma unroll
    for (int i = 0; i < 4; i++) {
        v[i] = Z4[t + i * 256];
        mx = fmaxf(mx, fmaxf(fmaxf(v[i].x, v[i].y), fmaxf(v[i].z, v[i].w)));
    }
    __shared__ float red[256];
    red[t] = mx;
    __syncthreads();
    for (int s = 128; s > 0; s >>= 1) {
        if (t < s) red[t] = fmaxf(red[t], red[t + s]);
        __syncthreads();
    }
    float m = red[0];
    __syncthreads();
    float sum = 0.f;
#pragma unroll
    for (int i = 0; i < 4; i++)
        sum += expf(v[i].x - m) + expf(v[i].y - m) + expf(v[i].z - m) + expf(v[i].w - m);
    red[t] = sum;
    __syncthreads();
    for (int s = 128; s > 0; s >>= 1) {
        if (t < s) red[t] += red[t + s];
        __syncthreads();
    }
    if (t == 0) {
        m_out[p] = m;
        d_out[p] = red[0];
    }
}

// ---------------------------------------------------------------------------
// gemmU (NN): U[p,j] = sum_l w[p,l]*Bgcols[l,j], w = exp(Z-m)/denom * mm[l]
// ---------------------------------------------------------------------------
__global__ __launch_bounds__(256) void gemmU_kernel(
    const float* __restrict__ Z, const float* __restrict__ m_buf,
    const float* __restrict__ denom_buf, const float* __restrict__ mmv,
    const float* __restrict__ Bg, float* __restrict__ U)
{
    __shared__ float As[64][17];
    __shared__ float Bs[16][68];

    int t = threadIdx.x;
    int c0 = blockIdx.x * 64;
    int p0 = blockIdx.y * 64;
    int tx = t & 15, ty = t >> 4;

    int ar = t >> 2, akq = (t & 3) * 4;
    int bkk = t >> 4, bc4 = (t & 15) * 4;

    float mrow = m_buf[p0 + ar];
    float dinv = 1.0f / denom_buf[p0 + ar];

    float acc[4][4] = {};

    for (int kt = 0; kt < LP; kt += 16) {
        float4 zv = *(const float4*)&Z[(long)(p0 + ar) * LP + kt + akq];
        float4 mq = *(const float4*)&mmv[kt + akq];
        As[ar][akq + 0] = expf(zv.x - mrow) * dinv * mq.x;
        As[ar][akq + 1] = expf(zv.y - mrow) * dinv * mq.y;
        As[ar][akq + 2] = expf(zv.z - mrow) * dinv * mq.z;
        As[ar][akq + 3] = expf(zv.w - mrow) * dinv * mq.w;
        float4 bv = *(const float4*)&Bg[(long)(kt + bkk) * N2 + c0 + bc4];
        *(float4*)&Bs[bkk][bc4] = bv;
        __syncthreads();
#pragma unroll
        for (int kk = 0; kk < 16; kk++) {
            float a[4];
#pragma unroll
            for (int i = 0; i < 4; i++) a[i] = As[ty * 4 + i][kk];
            float4 bq = *(const float4*)&Bs[kk][tx * 4];
#pragma unroll
            for (int i = 0; i < 4; i++) {
                acc[i][0] += a[i] * bq.x;
                acc[i][1] += a[i] * bq.y;
                acc[i][2] += a[i] * bq.z;
                acc[i][3] += a[i] * bq.w;
            }
        }
        __syncthreads();
    }

#pragma unroll
    for (int i = 0; i < 4; i++) {
        float4 o = make_float4(acc[i][0], acc[i][1], acc[i][2], acc[i][3]);
        *(float4*)&U[(long)(p0 + ty * 4 + i) * N2 + c0 + tx * 4] = o;
    }
}

// ---------------------------------------------------------------------------
// gather / overlap-add (upright), FP32 OUTPUT:
// out[b,c,oy,ox] = 0.25 * sum over valid (dy,dx) of U[(y,x), c*16+dy*4+dx],
// oy = 2y-1+dy, ox = 2x-1+dx.
// ---------------------------------------------------------------------------
__global__ __launch_bounds__(256) void gather_kernel(
    const float* __restrict__ U, float* __restrict__ out)
{
    int idx = blockIdx.x * 256 + threadIdx.x;
    int ox = idx & 127;
    int t1 = idx >> 7;
    int oy = t1 & 127;
    int t2 = t1 >> 7;
    int c = t2 & 15;
    int b = t2 >> 4;

    float sum = 0.f;
    int d0y = (oy + 1) & 1, d0x = (ox + 1) & 1;
#pragma unroll
    for (int iy = 0; iy < 2; iy++) {
        int dy = d0y + 2 * iy;
        int y = (oy + 1 - dy) >> 1;
        if (y < 0 || y > 63) continue;
#pragma unroll
        for (int ix = 0; ix < 2; ix++) {
            int dx = d0x + 2 * ix;
            int x = (ox + 1 - dx) >> 1;
            if (x < 0 || x > 63) continue;
            sum += U[((long)b * LP + y * 64 + x) * N2 + c * 16 + dy * 4 + dx];
        }
    }
    out[idx] = sum * 0.25f;
}

// ---------------------------------------------------------------------------
extern "C" void kernel_launch(void* const* d_in, const int* in_sizes, int n_in,
                              void* d_out, int out_size, void* d_ws, size_t ws_size,
                              hipStream_t stream)
{
    const void* fg   = d_in[0];
    const void* bg   = d_in[1];
    const void* mask = d_in[2];
    float* out = (float*)d_out;     // FP32 output (round-16 probe evidence)

    char* w = (char*)d_ws;
    size_t o = 0;
    int*   flag   = (int*)(w + o);   o += 16;
    float* Fgp    = (float*)(w + o); o += (size_t)BB * LP * K1 * 4;
    float* Kcols  = (float*)(w + o); o += (size_t)BB * LP * K1 * 4;
    float* Bgcols = (float*)(w + o); o += (size_t)BB * LP * N2 * 4;
    float* U      = (float*)(w + o); o += (size_t)BB * LP * N2 * 4;
    float* mmg    = (float*)(w + o); o += (size_t)BB * LP * 4;
    float* mbuf   = (float*)(w + o); o += (size_t)LP * 4;
    float* dbuf   = (float*)(w + o); o += (size_t)LP * 4;
    float* Z      = (float*)(w + o); o += (size_t)LP * LP * 4;

    detect_kernel<<<1, 64, 0, stream>>>((const unsigned int*)fg, flag);
    prep_kernel<<<BB * LP, 256, 0, stream>>>(fg, bg, mask, flag, Fgp, Kcols, mmg);
    bgcols_kernel<<<BB * LP, 256, 0, stream>>>(bg, flag, Bgcols);

    for (int b = 0; b < BB; b++) {
        gemmZ_kernel<<<dim3(64, 64), 256, 0, stream>>>(
            Fgp + (size_t)b * LP * K1, Kcols + (size_t)b * LP * K1,
            mmg + (size_t)b * LP, Z);
        stats_kernel<<<LP, 256, 0, stream>>>(Z, mbuf, dbuf);
        gemmU_kernel<<<dim3(4, 64), 256, 0, stream>>>(
            Z, mbuf, dbuf, mmg + (size_t)b * LP,
            Bgcols + (size_t)b * LP * N2, U + (size_t)b * LP * N2);
    }

    gather_kernel<<<(BB * CC * HH * WW) / 256, 256, 0, stream>>>(U, out);
}

// Round 18
// 1672.347 us; speedup vs baseline: 1.9544x; 1.9544x over previous
//
#include <hip/hip_runtime.h>
#include <hip/hip_bf16.h>

#define BB 8
#define CC 16
#define HH 128
#define WW 128
#define HD 64
#define WD 64
#define LP 4096
#define K1 144
#define N2 256

typedef __attribute__((ext_vector_type(8))) short bf16x8;
typedef __attribute__((ext_vector_type(4))) float f32x4;

__device__ __forceinline__ unsigned short pack_rne(float x) {
    unsigned int u = __float_as_uint(x);
    return (unsigned short)((u + 0x7FFFu + ((u >> 16) & 1u)) >> 16);
}

// Read input element idx as float, honoring detected storage dtype.
__device__ __forceinline__ float ld_in(const void* p, long idx, int bf) {
    if (bf) {
        unsigned short u = ((const unsigned short*)p)[idx];
        return __uint_as_float(((unsigned int)u) << 16);
    }
    return ((const float*)p)[idx];
}

// ---------------------------------------------------------------------------
__global__ void detect_kernel(const unsigned int* __restrict__ w, int* __restrict__ flag) {
    if (threadIdx.x == 0) {
        int cnt = 0;
        for (int i = 0; i < 256; i++) {
            unsigned int e = (w[i] >> 7) & 0xFF;
            if (e >= 100 && e <= 140) cnt++;
        }
        *flag = (cnt >= 192) ? 1 : 0;
    }
}

// ---------------------------------------------------------------------------
// prep: Fgp[b,l,k] fp32; Kcols[b,l,k] = bg/norm; mmg[b,l] = mm.
// ---------------------------------------------------------------------------
__global__ __launch_bounds__(256) void prep_kernel(
    const void* __restrict__ fg, const void* __restrict__ bg,
    const void* __restrict__ mask, const int* __restrict__ flagp,
    float* __restrict__ Fgp, float* __restrict__ Kcols, float* __restrict__ mmg)
{
    int bf = *flagp;
    int bl = blockIdx.x;
    int b = bl >> 12, l = bl & 4095;
    int py = l >> 6, px = l & 63;
    int tid = threadIdx.x;
    __shared__ float sq[160];
    __shared__ float nrm_sh;

    float fgv = 0.f, bgv = 0.f;
    if (tid < K1) {
        int c = tid / 9;
        int r9 = tid - c * 9;
        int ky = r9 / 3, kx = r9 - ky * 3;
        int yy = py + ky - 1, xx = px + kx - 1;
        if (yy >= 0 && yy < HD && xx >= 0 && xx < WD) {
            long base = ((long)(b * CC + c) * HH + 2 * yy) * WW + 2 * xx;
            fgv = ld_in(fg, base, bf);
            bgv = ld_in(bg, base, bf);
        }
        sq[tid] = bgv * bgv;
    }
    __syncthreads();
    if (tid == 0) {
        float S = 0.f;
        for (int k = 0; k < K1; k++) S += sq[k];
        nrm_sh = fmaxf(sqrtf(S), 1e-4f);
    }
    __syncthreads();
    float nrm = nrm_sh;

    if (tid < K1) {
        long base = (long)bl * K1 + tid;
        Fgp[base] = fgv;
        Kcols[base] = bgv / nrm;
    }
    if (tid == 0) {
        float s9 = 0.f;
        for (int ky = 0; ky < 3; ky++)
            for (int kx = 0; kx < 3; kx++) {
                int yy = py + ky - 1, xx = px + kx - 1;
                if (yy >= 0 && yy < HD && xx >= 0 && xx < WD)
                    s9 += ld_in(mask, ((long)b * HH + 2 * yy) * WW + 2 * xx, bf);
            }
        mmg[bl] = (s9 == 0.0f) ? 1.0f : 0.0f;
    }
}

// ---------------------------------------------------------------------------
// vT: VT[b][j][l] bf16 (j=(c,dy,dx) 0..255, l 0..4095). Row-contiguous in l:
// thread j writes 16 consecutive l as 2x uint4.
// ---------------------------------------------------------------------------
__global__ __launch_bounds__(256) void vT_kernel(
    const void* __restrict__ bg, const int* __restrict__ flagp,
    unsigned short* __restrict__ VT)
{
    int bf = *flagp;
    int l0 = blockIdx.x * 16;
    int b = blockIdx.y;
    int j = threadIdx.x;
    int c = j >> 4, dy = (j >> 2) & 3, dx = j & 3;

    unsigned short buf[16];
#pragma unroll
    for (int i = 0; i < 16; i++) {
        int l = l0 + i;
        int ly = l >> 6, lx = l & 63;
        int Y = 2 * ly + dy - 1, X = 2 * lx + dx - 1;
        float v = 0.f;
        if (Y >= 0 && Y < HH && X >= 0 && X < WW)
            v = ld_in(bg, ((long)(b * CC + c) * HH + Y) * WW + X, bf);
        buf[i] = pack_rne(v);
    }
    uint4* dst = (uint4*)&VT[((size_t)(b * N2 + j)) * LP + l0];
    dst[0] = *(uint4*)&buf[0];
    dst[1] = *(uint4*)&buf[8];
}

// ---------------------------------------------------------------------------
__global__ __launch_bounds__(256) void zeroU_kernel(float4* __restrict__ U4) {
    U4[blockIdx.x * 256 + threadIdx.x] = make_float4(0.f, 0.f, 0.f, 0.f);
}

// ---------------------------------------------------------------------------
// gemmZ (NT): Z[p,l] = mm[l] ? 10 * dot144(Fgp[p], Kcols[l]) : 0   (fp32)
// ---------------------------------------------------------------------------
__global__ __launch_bounds__(256) void gemmZ_kernel(
    const float* __restrict__ A, const float* __restrict__ Bm,
    const float* __restrict__ mmv, float* __restrict__ Z)
{
    __shared__ float As[64][17];
    __shared__ float Bs[64][17];

    int t = threadIdx.x;
    int l0 = blockIdx.x * 64, p0 = blockIdx.y * 64;
    int lr = t >> 2, kq = (t & 3) * 4;
    int tx = t & 15, ty = t >> 4;

    float acc[4][4] = {};

    for (int kt = 0; kt < K1; kt += 16) {
        float4 av = *(const float4*)&A[(long)(p0 + lr) * K1 + kt + kq];
        float4 bv = *(const float4*)&Bm[(long)(l0 + lr) * K1 + kt + kq];
        As[lr][kq + 0] = av.x; As[lr][kq + 1] = av.y; As[lr][kq + 2] = av.z; As[lr][kq + 3] = av.w;
        Bs[lr][kq + 0] = bv.x; Bs[lr][kq + 1] = bv.y; Bs[lr][kq + 2] = bv.z; Bs[lr][kq + 3] = bv.w;
        __syncthreads();
#pragma unroll
        for (int kk = 0; kk < 16; kk++) {
            float a[4], bb[4];
#pragma unroll
            for (int i = 0; i < 4; i++) a[i] = As[ty * 4 + i][kk];
#pragma unroll
            for (int j = 0; j < 4; j++) bb[j] = Bs[tx * 4 + j][kk];
#pragma unroll
            for (int i = 0; i < 4; i++)
#pragma unroll
                for (int j = 0; j < 4; j++) acc[i][j] += a[i] * bb[j];
        }
        __syncthreads();
    }

    float mj[4];
#pragma unroll
    for (int j = 0; j < 4; j++) mj[j] = mmv[l0 + tx * 4 + j];
#pragma unroll
    for (int i = 0; i < 4; i++) {
        float z[4];
#pragma unroll
        for (int j = 0; j < 4; j++)
            z[j] = (mj[j] > 0.f) ? 10.0f * acc[i][j] : 0.f;
        *(float4*)&Z[(long)(p0 + ty * 4 + i) * LP + l0 + tx * 4] =
            make_float4(z[0], z[1], z[2], z[3]);
    }
}

// ---------------------------------------------------------------------------
// statsW: per p-row: m = max(Z), denom = sum exp(Z-m); then writes
// W[p,l] = bf16( exp(z-m)/denom * mm[l] ) IN-PLACE over the row's first 8 KB.
// All Z reads complete before the final reduction barrier -> in-place safe.
// ---------------------------------------------------------------------------
__global__ __launch_bounds__(256) void statsW_kernel(
    float* __restrict__ Z, const float* __restrict__ mmv)
{
    int p = blockIdx.x;
    int t = threadIdx.x;
    float4* Z4 = (float4*)(Z + (size_t)p * LP);
    __shared__ float red[256];

    float4 z[4];
    float mx = -1e30f;
#pragma unroll
    for (int i = 0; i < 4; i++) {
        z[i] = Z4[t + 256 * i];
        mx = fmaxf(mx, fmaxf(fmaxf(z[i].x, z[i].y), fmaxf(z[i].z, z[i].w)));
    }
    red[t] = mx;
    __syncthreads();
    for (int s = 128; s > 0; s >>= 1) {
        if (t < s) red[t] = fmaxf(red[t], red[t + s]);
        __syncthreads();
    }
    float m = red[0];
    __syncthreads();

    float4 e[4];
    float sum = 0.f;
#pragma unroll
    for (int i = 0; i < 4; i++) {
        e[i].x = expf(z[i].x - m);
        e[i].y = expf(z[i].y - m);
        e[i].z = expf(z[i].z - m);
        e[i].w = expf(z[i].w - m);
        sum += e[i].x + e[i].y + e[i].z + e[i].w;
    }
    red[t] = sum;
    __syncthreads();
    for (int s = 128; s > 0; s >>= 1) {
        if (t < s) red[t] += red[t + s];
        __syncthreads();
    }
    float dinv = 1.0f / red[0];

    const float4* mm4 = (const float4*)mmv;
    uint2* W2 = (uint2*)(Z + (size_t)p * LP);
#pragma unroll
    for (int i = 0; i < 4; i++) {
        float4 mm = mm4[t + 256 * i];
        uint2 pk;
        pk.x = (unsigned)pack_rne(e[i].x * dinv * mm.x) |
               ((unsigned)pack_rne(e[i].y * dinv * mm.y) << 16);
        pk.y = (unsigned)pack_rne(e[i].z * dinv * mm.z) |
               ((unsigned)pack_rne(e[i].w * dinv * mm.w) << 16);
        W2[t + 256 * i] = pk;
    }
}

// ---------------------------------------------------------------------------
// gemmU via bf16 MFMA: U[p,j] += sum_l W[p,l]*VT[j,l].
// Tile 128x64, BK=32, split-K=8 (atomicAdd into zeroed U).
// W row stride = 8192 ushorts (aliases Z rows). Layouts per m89/m120:
// A-frag: A[m=lane&15][k=(lane>>4)*8+j]; B-frag same addressing off VT rows;
// C/D: col=lane&15, row=(lane>>4)*4+reg.
// ---------------------------------------------------------------------------
__global__ __launch_bounds__(256) void gemmU_mfma_kernel(
    const unsigned short* __restrict__ W16,   // [4096][stride 8192]
    const unsigned short* __restrict__ VT,    // [256][4096]
    float* __restrict__ U)                    // [4096][256]
{
    __shared__ unsigned short Ws[128][40];
    __shared__ unsigned short Vs[64][40];

    int t = threadIdx.x;
    int c0 = blockIdx.x * 64;
    int p0 = blockIdx.y * 128;
    int kz = blockIdx.z;

    int wave = t >> 6, lane = t & 63;
    int lrow = lane & 15, lq = lane >> 4;

    f32x4 zero4 = {0.f, 0.f, 0.f, 0.f};
    f32x4 acc[2][4];
#pragma unroll
    for (int i = 0; i < 2; i++)
#pragma unroll
        for (int n = 0; n < 4; n++) acc[i][n] = zero4;

    int wrow = t >> 1, whalf = t & 1;
    int vrow = t >> 2, vq = t & 3;

    for (int l0 = kz * 512; l0 < kz * 512 + 512; l0 += 32) {
        const uint4* wg = (const uint4*)&W16[(size_t)(p0 + wrow) * 8192 + l0 + whalf * 16];
        uint4 w0 = wg[0];
        uint4 w1 = wg[1];
        uint4 v0 = *(const uint4*)&VT[(size_t)(c0 + vrow) * LP + l0 + vq * 8];
        __syncthreads();                       // prior frag reads done
        *(uint4*)&Ws[wrow][whalf * 16] = w0;
        *(uint4*)&Ws[wrow][whalf * 16 + 8] = w1;
        *(uint4*)&Vs[vrow][vq * 8] = v0;
        __syncthreads();                       // tiles staged

        bf16x8 a0 = *(const bf16x8*)&Ws[wave * 32 + lrow][lq * 8];
        bf16x8 a1 = *(const bf16x8*)&Ws[wave * 32 + 16 + lrow][lq * 8];
        bf16x8 b0 = *(const bf16x8*)&Vs[lrow][lq * 8];
        bf16x8 b1 = *(const bf16x8*)&Vs[16 + lrow][lq * 8];
        bf16x8 b2 = *(const bf16x8*)&Vs[32 + lrow][lq * 8];
        bf16x8 b3 = *(const bf16x8*)&Vs[48 + lrow][lq * 8];

        acc[0][0] = __builtin_amdgcn_mfma_f32_16x16x32_bf16(a0, b0, acc[0][0], 0, 0, 0);
        acc[0][1] = __builtin_amdgcn_mfma_f32_16x16x32_bf16(a0, b1, acc[0][1], 0, 0, 0);
        acc[0][2] = __builtin_amdgcn_mfma_f32_16x16x32_bf16(a0, b2, acc[0][2], 0, 0, 0);
        acc[0][3] = __builtin_amdgcn_mfma_f32_16x16x32_bf16(a0, b3, acc[0][3], 0, 0, 0);
        acc[1][0] = __builtin_amdgcn_mfma_f32_16x16x32_bf16(a1, b0, acc[1][0], 0, 0, 0);
        acc[1][1] = __builtin_amdgcn_mfma_f32_16x16x32_bf16(a1, b1, acc[1][1], 0, 0, 0);
        acc[1][2] = __builtin_amdgcn_mfma_f32_16x16x32_bf16(a1, b2, acc[1][2], 0, 0, 0);
        acc[1][3] = __builtin_amdgcn_mfma_f32_16x16x32_bf16(a1, b3, acc[1][3], 0, 0, 0);
    }

#pragma unroll
    for (int i = 0; i < 2; i++) {
#pragma unroll
        for (int n = 0; n < 4; n++) {
            int row = p0 + wave * 32 + i * 16 + lq * 4;
            int col = c0 + n * 16 + lrow;
#pragma unroll
            for (int r = 0; r < 4; r++)
                atomicAdd(&U[(size_t)(row + r) * N2 + col], acc[i][n][r]);
        }
    }
}

// ---------------------------------------------------------------------------
// gather / overlap-add (upright), fp32 out:
// out[b,c,oy,ox] = 0.25 * sum over valid (dy,dx) of U[(y,x), c*16+dy*4+dx]
// ---------------------------------------------------------------------------
__global__ __launch_bounds__(256) void gather_kernel(
    const float* __restrict__ U, float* __restrict__ out)
{
    int idx = blockIdx.x * 256 + threadIdx.x;
    int ox = idx & 127;
    int t1 = idx >> 7;
    int oy = t1 & 127;
    int t2 = t1 >> 7;
    int c = t2 & 15;
    int b = t2 >> 4;

    float sum = 0.f;
    int d0y = (oy + 1) & 1, d0x = (ox + 1) & 1;
#pragma unroll
    for (int iy = 0; iy < 2; iy++) {
        int dy = d0y + 2 * iy;
        int y = (oy + 1 - dy) >> 1;
        if (y < 0 || y > 63) continue;
#pragma unroll
        for (int ix = 0; ix < 2; ix++) {
            int dx = d0x + 2 * ix;
            int x = (ox + 1 - dx) >> 1;
            if (x < 0 || x > 63) continue;
            sum += U[((long)b * LP + y * 64 + x) * N2 + c * 16 + dy * 4 + dx];
        }
    }
    out[idx] = sum * 0.25f;
}

// ---------------------------------------------------------------------------
extern "C" void kernel_launch(void* const* d_in, const int* in_sizes, int n_in,
                              void* d_out, int out_size, void* d_ws, size_t ws_size,
                              hipStream_t stream)
{
    const void* fg   = d_in[0];
    const void* bg   = d_in[1];
    const void* mask = d_in[2];
    float* out = (float*)d_out;

    char* w = (char*)d_ws;
    size_t o = 0;
    int*            flag = (int*)(w + o);            o += 16;
    float*          Fgp  = (float*)(w + o);          o += (size_t)BB * LP * K1 * 4;  // 18.9 MB
    float*          Kcols= (float*)(w + o);          o += (size_t)BB * LP * K1 * 4;  // 18.9 MB
    unsigned short* VT   = (unsigned short*)(w + o); o += (size_t)BB * N2 * LP * 2;  // 16.8 MB
    float*          U    = (float*)(w + o);          o += (size_t)BB * LP * N2 * 4;  // 33.6 MB
    float*          mmg  = (float*)(w + o);          o += (size_t)BB * LP * 4;
    float*          Z    = (float*)(w + o);          o += (size_t)LP * LP * 4;       // 67.1 MB (tot ~155 MB)

    detect_kernel<<<1, 64, 0, stream>>>((const unsigned int*)fg, flag);
    prep_kernel<<<BB * LP, 256, 0, stream>>>(fg, bg, mask, flag, Fgp, Kcols, mmg);
    vT_kernel<<<dim3(LP / 16, BB), 256, 0, stream>>>(bg, flag, VT);
    zeroU_kernel<<<(BB * LP * N2 / 4) / 256, 256, 0, stream>>>((float4*)U);

    for (int b = 0; b < BB; b++) {
        gemmZ_kernel<<<dim3(64, 64), 256, 0, stream>>>(
            Fgp + (size_t)b * LP * K1, Kcols + (size_t)b * LP * K1,
            mmg + (size_t)b * LP, Z);
        statsW_kernel<<<LP, 256, 0, stream>>>(Z, mmg + (size_t)b * LP);
        gemmU_mfma_kernel<<<dim3(4, 32, 8), 256, 0, stream>>>(
            (const unsigned short*)Z, VT + (size_t)b * N2 * LP,
            U + (size_t)b * LP * N2);
    }

    gather_kernel<<<(BB * CC * HH * WW) / 256, 256, 0, stream>>>(U, out);
}

// Round 19
// 1186.651 us; speedup vs baseline: 2.7543x; 1.4093x over previous
//
#include <hip/hip_runtime.h>
#include <hip/hip_bf16.h>

#define BB 8
#define CC 16
#define HH 128
#define WW 128
#define HD 64
#define WD 64
#define LP 4096
#define K1 144
#define KP 160   // K1 padded to multiple of 32 for MFMA K-loop

typedef __attribute__((ext_vector_type(8))) short bf16x8;
typedef __attribute__((ext_vector_type(4))) float f32x4;

#define N2 256

__device__ __forceinline__ unsigned short pack_rne(float x) {
    unsigned int u = __float_as_uint(x);
    return (unsigned short)((u + 0x7FFFu + ((u >> 16) & 1u)) >> 16);
}
__device__ __forceinline__ float bf2f(unsigned short u) {
    return __uint_as_float(((unsigned int)u) << 16);
}

// Read input element idx as float, honoring detected storage dtype.
__device__ __forceinline__ float ld_in(const void* p, long idx, int bf) {
    if (bf) return bf2f(((const unsigned short*)p)[idx]);
    return ((const float*)p)[idx];
}

// ---------------------------------------------------------------------------
__global__ void detect_kernel(const unsigned int* __restrict__ w, int* __restrict__ flag) {
    if (threadIdx.x == 0) {
        int cnt = 0;
        for (int i = 0; i < 256; i++) {
            unsigned int e = (w[i] >> 7) & 0xFF;
            if (e >= 100 && e <= 140) cnt++;
        }
        *flag = (cnt >= 192) ? 1 : 0;
    }
}

// ---------------------------------------------------------------------------
// prep: hi/lo bf16 split of Fgp and Kcols = bg/norm, zero-padded to KP;
// mmg[b,l] = mm. One block per (b,l).
// ---------------------------------------------------------------------------
__global__ __launch_bounds__(256) void prep_kernel(
    const void* __restrict__ fg, const void* __restrict__ bg,
    const void* __restrict__ mask, const int* __restrict__ flagp,
    unsigned short* __restrict__ Fh, unsigned short* __restrict__ Fl,
    unsigned short* __restrict__ Kh, unsigned short* __restrict__ Kl,
    float* __restrict__ mmg)
{
    int bf = *flagp;
    int bl = blockIdx.x;
    int b = bl >> 12, l = bl & 4095;
    int py = l >> 6, px = l & 63;
    int tid = threadIdx.x;
    __shared__ float sq[160];
    __shared__ float nrm_sh;

    float fgv = 0.f, bgv = 0.f;
    if (tid < K1) {
        int c = tid / 9;
        int r9 = tid - c * 9;
        int ky = r9 / 3, kx = r9 - ky * 3;
        int yy = py + ky - 1, xx = px + kx - 1;
        if (yy >= 0 && yy < HD && xx >= 0 && xx < WD) {
            long base = ((long)(b * CC + c) * HH + 2 * yy) * WW + 2 * xx;
            fgv = ld_in(fg, base, bf);
            bgv = ld_in(bg, base, bf);
        }
        sq[tid] = bgv * bgv;
    }
    __syncthreads();
    if (tid == 0) {
        float S = 0.f;
        for (int k = 0; k < K1; k++) S += sq[k];
        nrm_sh = fmaxf(sqrtf(S), 1e-4f);
    }
    __syncthreads();
    float nrm = nrm_sh;

    if (tid < KP) {
        long base = (long)bl * KP + tid;
        float kv = (tid < K1) ? (bgv / nrm) : 0.f;   // bgv=0 beyond K1 anyway
        unsigned short fh = pack_rne(fgv);
        unsigned short fl = pack_rne(fgv - bf2f(fh));
        unsigned short kh = pack_rne(kv);
        unsigned short kl = pack_rne(kv - bf2f(kh));
        Fh[base] = fh; Fl[base] = fl;
        Kh[base] = kh; Kl[base] = kl;
    }
    if (tid == 0) {
        float s9 = 0.f;
        for (int ky = 0; ky < 3; ky++)
            for (int kx = 0; kx < 3; kx++) {
                int yy = py + ky - 1, xx = px + kx - 1;
                if (yy >= 0 && yy < HD && xx >= 0 && xx < WD)
                    s9 += ld_in(mask, ((long)b * HH + 2 * yy) * WW + 2 * xx, bf);
            }
        mmg[bl] = (s9 == 0.0f) ? 1.0f : 0.0f;
    }
}

// ---------------------------------------------------------------------------
// vT: VT[b][j][l] bf16
// ---------------------------------------------------------------------------
__global__ __launch_bounds__(256) void vT_kernel(
    const void* __restrict__ bg, const int* __restrict__ flagp,
    unsigned short* __restrict__ VT)
{
    int bf = *flagp;
    int l0 = blockIdx.x * 16;
    int b = blockIdx.y;
    int j = threadIdx.x;
    int c = j >> 4, dy = (j >> 2) & 3, dx = j & 3;

    unsigned short buf[16];
#pragma unroll
    for (int i = 0; i < 16; i++) {
        int l = l0 + i;
        int ly = l >> 6, lx = l & 63;
        int Y = 2 * ly + dy - 1, X = 2 * lx + dx - 1;
        float v = 0.f;
        if (Y >= 0 && Y < HH && X >= 0 && X < WW)
            v = ld_in(bg, ((long)(b * CC + c) * HH + Y) * WW + X, bf);
        buf[i] = pack_rne(v);
    }
    uint4* dst = (uint4*)&VT[((size_t)(b * N2 + j)) * LP + l0];
    dst[0] = *(uint4*)&buf[0];
    dst[1] = *(uint4*)&buf[8];
}

// ---------------------------------------------------------------------------
__global__ __launch_bounds__(256) void zeroU_kernel(float4* __restrict__ U4) {
    U4[blockIdx.x * 256 + threadIdx.x] = make_float4(0.f, 0.f, 0.f, 0.f);
}

// ---------------------------------------------------------------------------
// gemmZ via split-bf16 MFMA (fp32-accurate):
// Z[p,l] = mm[l] ? 10 * sum_k F[p,k]*K[l,k] : 0, with x*y ~ xh*yh+xh*yl+xl*yh.
// Tile 128p x 64l, BK=32, 4 waves. A-frag m=lane&15,k=(lane>>4)*8+j; C/D
// col=lane&15,row=(lane>>4)*4+reg  [m89/m120 layouts, HW-validated in r18].
// ---------------------------------------------------------------------------
__global__ __launch_bounds__(256) void gemmZ_mfma_kernel(
    const unsigned short* __restrict__ Ah, const unsigned short* __restrict__ Al,
    const unsigned short* __restrict__ Bh, const unsigned short* __restrict__ Bl,
    const float* __restrict__ mmv, float* __restrict__ Z)
{
    __shared__ unsigned short AhS[128][40];
    __shared__ unsigned short AlS[128][40];
    __shared__ unsigned short BhS[64][40];
    __shared__ unsigned short BlS[64][40];

    int t = threadIdx.x;
    int l0 = blockIdx.x * 64, p0 = blockIdx.y * 128;
    int wave = t >> 6, lane = t & 63;
    int lrow = lane & 15, lq = lane >> 4;

    f32x4 zero4 = {0.f, 0.f, 0.f, 0.f};
    f32x4 acc[2][4];
#pragma unroll
    for (int i = 0; i < 2; i++)
#pragma unroll
        for (int n = 0; n < 4; n++) acc[i][n] = zero4;

    int arow = t >> 1, ahalf = (t & 1) * 16;   // 128 rows x 2 halves
    int brow = t >> 2, bq = (t & 3) * 8;       // 64 rows x 4 quads

    for (int k0 = 0; k0 < KP; k0 += 32) {
        size_t abase = (size_t)(p0 + arow) * KP + k0 + ahalf;
        size_t bbase = (size_t)(l0 + brow) * KP + k0 + bq;
        uint4 ah0 = *(const uint4*)&Ah[abase];
        uint4 ah1 = *(const uint4*)&Ah[abase + 8];
        uint4 al0 = *(const uint4*)&Al[abase];
        uint4 al1 = *(const uint4*)&Al[abase + 8];
        uint4 bh0 = *(const uint4*)&Bh[bbase];
        uint4 bl0 = *(const uint4*)&Bl[bbase];
        __syncthreads();
        *(uint4*)&AhS[arow][ahalf] = ah0;
        *(uint4*)&AhS[arow][ahalf + 8] = ah1;
        *(uint4*)&AlS[arow][ahalf] = al0;
        *(uint4*)&AlS[arow][ahalf + 8] = al1;
        *(uint4*)&BhS[brow][bq] = bh0;
        *(uint4*)&BlS[brow][bq] = bl0;
        __syncthreads();

        bf16x8 ah[2], al[2], bh[4], blo[4];
#pragma unroll
        for (int i = 0; i < 2; i++) {
            ah[i] = *(const bf16x8*)&AhS[wave * 32 + i * 16 + lrow][lq * 8];
            al[i] = *(const bf16x8*)&AlS[wave * 32 + i * 16 + lrow][lq * 8];
        }
#pragma unroll
        for (int n = 0; n < 4; n++) {
            bh[n] = *(const bf16x8*)&BhS[n * 16 + lrow][lq * 8];
            blo[n] = *(const bf16x8*)&BlS[n * 16 + lrow][lq * 8];
        }
#pragma unroll
        for (int i = 0; i < 2; i++)
#pragma unroll
            for (int n = 0; n < 4; n++) {
                acc[i][n] = __builtin_amdgcn_mfma_f32_16x16x32_bf16(ah[i], bh[n], acc[i][n], 0, 0, 0);
                acc[i][n] = __builtin_amdgcn_mfma_f32_16x16x32_bf16(ah[i], blo[n], acc[i][n], 0, 0, 0);
                acc[i][n] = __builtin_amdgcn_mfma_f32_16x16x32_bf16(al[i], bh[n], acc[i][n], 0, 0, 0);
            }
    }

#pragma unroll
    for (int i = 0; i < 2; i++)
#pragma unroll
        for (int n = 0; n < 4; n++) {
            int row = p0 + wave * 32 + i * 16 + lq * 4;
            int col = l0 + n * 16 + lrow;
            float mmc = mmv[col];
#pragma unroll
            for (int r = 0; r < 4; r++) {
                float z = (mmc > 0.f) ? 10.0f * acc[i][n][r] : 0.f;
                Z[(size_t)(row + r) * LP + col] = z;
            }
        }
}

// ---------------------------------------------------------------------------
// statsW: softmax stats per row, then W[p,l] = bf16(exp(z-m)/denom * mm[l])
// in-place over the Z row prefix.
// ---------------------------------------------------------------------------
__global__ __launch_bounds__(256) void statsW_kernel(
    float* __restrict__ Z, const float* __restrict__ mmv)
{
    int p = blockIdx.x;
    int t = threadIdx.x;
    float4* Z4 = (float4*)(Z + (size_t)p * LP);
    __shared__ float red[256];

    float4 z[4];
    float mx = -1e30f;
#pragma unroll
    for (int i = 0; i < 4; i++) {
        z[i] = Z4[t + 256 * i];
        mx = fmaxf(mx, fmaxf(fmaxf(z[i].x, z[i].y), fmaxf(z[i].z, z[i].w)));
    }
    red[t] = mx;
    __syncthreads();
    for (int s = 128; s > 0; s >>= 1) {
        if (t < s) red[t] = fmaxf(red[t], red[t + s]);
        __syncthreads();
    }
    float m = red[0];
    __syncthreads();

    float4 e[4];
    float sum = 0.f;
#pragma unroll
    for (int i = 0; i < 4; i++) {
        e[i].x = expf(z[i].x - m);
        e[i].y = expf(z[i].y - m);
        e[i].z = expf(z[i].z - m);
        e[i].w = expf(z[i].w - m);
        sum += e[i].x + e[i].y + e[i].z + e[i].w;
    }
    red[t] = sum;
    __syncthreads();
    for (int s = 128; s > 0; s >>= 1) {
        if (t < s) red[t] += red[t + s];
        __syncthreads();
    }
    float dinv = 1.0f / red[0];

    const float4* mm4 = (const float4*)mmv;
    uint2* W2 = (uint2*)(Z + (size_t)p * LP);
#pragma unroll
    for (int i = 0; i < 4; i++) {
        float4 mm = mm4[t + 256 * i];
        uint2 pk;
        pk.x = (unsigned)pack_rne(e[i].x * dinv * mm.x) |
               ((unsigned)pack_rne(e[i].y * dinv * mm.y) << 16);
        pk.y = (unsigned)pack_rne(e[i].z * dinv * mm.z) |
               ((unsigned)pack_rne(e[i].w * dinv * mm.w) << 16);
        W2[t + 256 * i] = pk;
    }
}

// ---------------------------------------------------------------------------
// gemmU via bf16 MFMA, split-K=8 with fp32 atomics (r18, validated).
// ---------------------------------------------------------------------------
__global__ __launch_bounds__(256) void gemmU_mfma_kernel(
    const unsigned short* __restrict__ W16,   // [4096][stride 8192]
    const unsigned short* __restrict__ VT,    // [256][4096]
    float* __restrict__ U)                    // [4096][256]
{
    __shared__ unsigned short Ws[128][40];
    __shared__ unsigned short Vs[64][40];

    int t = threadIdx.x;
    int c0 = blockIdx.x * 64;
    int p0 = blockIdx.y * 128;
    int kz = blockIdx.z;

    int wave = t >> 6, lane = t & 63;
    int lrow = lane & 15, lq = lane >> 4;

    f32x4 zero4 = {0.f, 0.f, 0.f, 0.f};
    f32x4 acc[2][4];
#pragma unroll
    for (int i = 0; i < 2; i++)
#pragma unroll
        for (int n = 0; n < 4; n++) acc[i][n] = zero4;

    int wrow = t >> 1, whalf = t & 1;
    int vrow = t >> 2, vq = t & 3;

    for (int l0 = kz * 512; l0 < kz * 512 + 512; l0 += 32) {
        const uint4* wg = (const uint4*)&W16[(size_t)(p0 + wrow) * 8192 + l0 + whalf * 16];
        uint4 w0 = wg[0];
        uint4 w1 = wg[1];
        uint4 v0 = *(const uint4*)&VT[(size_t)(c0 + vrow) * LP + l0 + vq * 8];
        __syncthreads();
        *(uint4*)&Ws[wrow][whalf * 16] = w0;
        *(uint4*)&Ws[wrow][whalf * 16 + 8] = w1;
        *(uint4*)&Vs[vrow][vq * 8] = v0;
        __syncthreads();

        bf16x8 a0 = *(const bf16x8*)&Ws[wave * 32 + lrow][lq * 8];
        bf16x8 a1 = *(const bf16x8*)&Ws[wave * 32 + 16 + lrow][lq * 8];
        bf16x8 b0 = *(const bf16x8*)&Vs[lrow][lq * 8];
        bf16x8 b1 = *(const bf16x8*)&Vs[16 + lrow][lq * 8];
        bf16x8 b2 = *(const bf16x8*)&Vs[32 + lrow][lq * 8];
        bf16x8 b3 = *(const bf16x8*)&Vs[48 + lrow][lq * 8];

        acc[0][0] = __builtin_amdgcn_mfma_f32_16x16x32_bf16(a0, b0, acc[0][0], 0, 0, 0);
        acc[0][1] = __builtin_amdgcn_mfma_f32_16x16x32_bf16(a0, b1, acc[0][1], 0, 0, 0);
        acc[0][2] = __builtin_amdgcn_mfma_f32_16x16x32_bf16(a0, b2, acc[0][2], 0, 0, 0);
        acc[0][3] = __builtin_amdgcn_mfma_f32_16x16x32_bf16(a0, b3, acc[0][3], 0, 0, 0);
        acc[1][0] = __builtin_amdgcn_mfma_f32_16x16x32_bf16(a1, b0, acc[1][0], 0, 0, 0);
        acc[1][1] = __builtin_amdgcn_mfma_f32_16x16x32_bf16(a1, b1, acc[1][1], 0, 0, 0);
        acc[1][2] = __builtin_amdgcn_mfma_f32_16x16x32_bf16(a1, b2, acc[1][2], 0, 0, 0);
        acc[1][3] = __builtin_amdgcn_mfma_f32_16x16x32_bf16(a1, b3, acc[1][3], 0, 0, 0);
    }

#pragma unroll
    for (int i = 0; i < 2; i++) {
#pragma unroll
        for (int n = 0; n < 4; n++) {
            int row = p0 + wave * 32 + i * 16 + lq * 4;
            int col = c0 + n * 16 + lrow;
#pragma unroll
            for (int r = 0; r < 4; r++)
                atomicAdd(&U[(size_t)(row + r) * N2 + col], acc[i][n][r]);
        }
    }
}

// ---------------------------------------------------------------------------
// gather / overlap-add (upright), fp32 out
// ---------------------------------------------------------------------------
__global__ __launch_bounds__(256) void gather_kernel(
    const float* __restrict__ U, float* __restrict__ out)
{
    int idx = blockIdx.x * 256 + threadIdx.x;
    int ox = idx & 127;
    int t1 = idx >> 7;
    int oy = t1 & 127;
    int t2 = t1 >> 7;
    int c = t2 & 15;
    int b = t2 >> 4;

    float sum = 0.f;
    int d0y = (oy + 1) & 1, d0x = (ox + 1) & 1;
#pragma unroll
    for (int iy = 0; iy < 2; iy++) {
        int dy = d0y + 2 * iy;
        int y = (oy + 1 - dy) >> 1;
        if (y < 0 || y > 63) continue;
#pragma unroll
        for (int ix = 0; ix < 2; ix++) {
            int dx = d0x + 2 * ix;
            int x = (ox + 1 - dx) >> 1;
            if (x < 0 || x > 63) continue;
            sum += U[((long)b * LP + y * 64 + x) * N2 + c * 16 + dy * 4 + dx];
        }
    }
    out[idx] = sum * 0.25f;
}

// ---------------------------------------------------------------------------
extern "C" void kernel_launch(void* const* d_in, const int* in_sizes, int n_in,
                              void* d_out, int out_size, void* d_ws, size_t ws_size,
                              hipStream_t stream)
{
    const void* fg   = d_in[0];
    const void* bg   = d_in[1];
    const void* mask = d_in[2];
    float* out = (float*)d_out;

    char* w = (char*)d_ws;
    size_t o = 0;
    int*            flag = (int*)(w + o);            o += 16;
    unsigned short* Fh   = (unsigned short*)(w + o); o += (size_t)BB * LP * KP * 2;  // 10.5 MB
    unsigned short* Fl   = (unsigned short*)(w + o); o += (size_t)BB * LP * KP * 2;
    unsigned short* Kh   = (unsigned short*)(w + o); o += (size_t)BB * LP * KP * 2;
    unsigned short* Kl   = (unsigned short*)(w + o); o += (size_t)BB * LP * KP * 2;
    unsigned short* VT   = (unsigned short*)(w + o); o += (size_t)BB * N2 * LP * 2;  // 16.8 MB
    float*          U    = (float*)(w + o);          o += (size_t)BB * LP * N2 * 4;  // 33.6 MB
    float*          mmg  = (float*)(w + o);          o += (size_t)BB * LP * 4;
    float*          Z    = (float*)(w + o);          o += (size_t)LP * LP * 4;       // 67.1 MB (~160 MB total)

    detect_kernel<<<1, 64, 0, stream>>>((const unsigned int*)fg, flag);
    prep_kernel<<<BB * LP, 256, 0, stream>>>(fg, bg, mask, flag, Fh, Fl, Kh, Kl, mmg);
    vT_kernel<<<dim3(LP / 16, BB), 256, 0, stream>>>(bg, flag, VT);
    zeroU_kernel<<<(BB * LP * N2 / 4) / 256, 256, 0, stream>>>((float4*)U);

    for (int b = 0; b < BB; b++) {
        gemmZ_mfma_kernel<<<dim3(64, 32), 256, 0, stream>>>(
            Fh + (size_t)b * LP * KP, Fl + (size_t)b * LP * KP,
            Kh + (size_t)b * LP * KP, Kl + (size_t)b * LP * KP,
            mmg + (size_t)b * LP, Z);
        statsW_kernel<<<LP, 256, 0, stream>>>(Z, mmg + (size_t)b * LP);
        gemmU_mfma_kernel<<<dim3(4, 32, 8), 256, 0, stream>>>(
            (const unsigned short*)Z, VT + (size_t)b * N2 * LP,
            U + (size_t)b * LP * N2);
    }

    gather_kernel<<<(BB * CC * HH * WW) / 256, 256, 0, stream>>>(U, out);
}

// Round 20
// 1132.528 us; speedup vs baseline: 2.8860x; 1.0478x over previous
//
#include <hip/hip_runtime.h>
#include <hip/hip_bf16.h>

#define BB 8
#define CC 16
#define HH 128
#define WW 128
#define HD 64
#define WD 64
#define LP 4096
#define K1 144
#define KP 160
#define N2 256

typedef __attribute__((ext_vector_type(8))) short bf16x8;
typedef __attribute__((ext_vector_type(4))) float f32x4;

__device__ __forceinline__ unsigned short pack_rne(float x) {
    unsigned int u = __float_as_uint(x);
    return (unsigned short)((u + 0x7FFFu + ((u >> 16) & 1u)) >> 16);
}
__device__ __forceinline__ float bf2f(unsigned short u) {
    return __uint_as_float(((unsigned int)u) << 16);
}
__device__ __forceinline__ float ld_in(const void* p, long idx, int bf) {
    if (bf) return bf2f(((const unsigned short*)p)[idx]);
    return ((const float*)p)[idx];
}

// ---------------------------------------------------------------------------
__global__ void detect_kernel(const unsigned int* __restrict__ w, int* __restrict__ flag) {
    if (threadIdx.x == 0) {
        int cnt = 0;
        for (int i = 0; i < 256; i++) {
            unsigned int e = (w[i] >> 7) & 0xFF;
            if (e >= 100 && e <= 140) cnt++;
        }
        *flag = (cnt >= 192) ? 1 : 0;
    }
}

// ---------------------------------------------------------------------------
// prep: hi/lo bf16 split of Fgp and Kcols = bg/norm, zero-padded to KP;
// mmg[b,l] = mm.
// ---------------------------------------------------------------------------
__global__ __launch_bounds__(256) void prep_kernel(
    const void* __restrict__ fg, const void* __restrict__ bg,
    const void* __restrict__ mask, const int* __restrict__ flagp,
    unsigned short* __restrict__ Fh, unsigned short* __restrict__ Fl,
    unsigned short* __restrict__ Kh, unsigned short* __restrict__ Kl,
    float* __restrict__ mmg)
{
    int bf = *flagp;
    int bl = blockIdx.x;
    int b = bl >> 12, l = bl & 4095;
    int py = l >> 6, px = l & 63;
    int tid = threadIdx.x;
    __shared__ float sq[160];
    __shared__ float nrm_sh;

    float fgv = 0.f, bgv = 0.f;
    if (tid < K1) {
        int c = tid / 9;
        int r9 = tid - c * 9;
        int ky = r9 / 3, kx = r9 - ky * 3;
        int yy = py + ky - 1, xx = px + kx - 1;
        if (yy >= 0 && yy < HD && xx >= 0 && xx < WD) {
            long base = ((long)(b * CC + c) * HH + 2 * yy) * WW + 2 * xx;
            fgv = ld_in(fg, base, bf);
            bgv = ld_in(bg, base, bf);
        }
        sq[tid] = bgv * bgv;
    }
    __syncthreads();
    if (tid == 0) {
        float S = 0.f;
        for (int k = 0; k < K1; k++) S += sq[k];
        nrm_sh = fmaxf(sqrtf(S), 1e-4f);
    }
    __syncthreads();
    float nrm = nrm_sh;

    if (tid < KP) {
        long base = (long)bl * KP + tid;
        float kv = (tid < K1) ? (bgv / nrm) : 0.f;
        unsigned short fh = pack_rne(fgv);
        unsigned short fl = pack_rne(fgv - bf2f(fh));
        unsigned short kh = pack_rne(kv);
        unsigned short kl = pack_rne(kv - bf2f(kh));
        Fh[base] = fh; Fl[base] = fl;
        Kh[base] = kh; Kl[base] = kl;
    }
    if (tid == 0) {
        float s9 = 0.f;
        for (int ky = 0; ky < 3; ky++)
            for (int kx = 0; kx < 3; kx++) {
                int yy = py + ky - 1, xx = px + kx - 1;
                if (yy >= 0 && yy < HD && xx >= 0 && xx < WD)
                    s9 += ld_in(mask, ((long)b * HH + 2 * yy) * WW + 2 * xx, bf);
            }
        mmg[bl] = (s9 == 0.0f) ? 1.0f : 0.0f;
    }
}

// ---------------------------------------------------------------------------
__global__ __launch_bounds__(256) void vT_kernel(
    const void* __restrict__ bg, const int* __restrict__ flagp,
    unsigned short* __restrict__ VT)
{
    int bf = *flagp;
    int l0 = blockIdx.x * 16;
    int b = blockIdx.y;
    int j = threadIdx.x;
    int c = j >> 4, dy = (j >> 2) & 3, dx = j & 3;

    unsigned short buf[16];
#pragma unroll
    for (int i = 0; i < 16; i++) {
        int l = l0 + i;
        int ly = l >> 6, lx = l & 63;
        int Y = 2 * ly + dy - 1, X = 2 * lx + dx - 1;
        float v = 0.f;
        if (Y >= 0 && Y < HH && X >= 0 && X < WW)
            v = ld_in(bg, ((long)(b * CC + c) * HH + Y) * WW + X, bf);
        buf[i] = pack_rne(v);
    }
    uint4* dst = (uint4*)&VT[((size_t)(b * N2 + j)) * LP + l0];
    dst[0] = *(uint4*)&buf[0];
    dst[1] = *(uint4*)&buf[8];
}

// ---------------------------------------------------------------------------
__global__ __launch_bounds__(256) void zeroU_kernel(float4* __restrict__ U4) {
    U4[blockIdx.x * 256 + threadIdx.x] = make_float4(0.f, 0.f, 0.f, 0.f);
}

// ---------------------------------------------------------------------------
// gemmZ via split-bf16 MFMA (fp32-accurate), 128x64 tile, BK=32 (r18/r19).
// ---------------------------------------------------------------------------
__global__ __launch_bounds__(256) void gemmZ_mfma_kernel(
    const unsigned short* __restrict__ Ah, const unsigned short* __restrict__ Al,
    const unsigned short* __restrict__ Bh, const unsigned short* __restrict__ Bl,
    const float* __restrict__ mmv, float* __restrict__ Z)
{
    __shared__ unsigned short AhS[128][40];
    __shared__ unsigned short AlS[128][40];
    __shared__ unsigned short BhS[64][40];
    __shared__ unsigned short BlS[64][40];

    int t = threadIdx.x;
    int l0 = blockIdx.x * 64, p0 = blockIdx.y * 128;
    int wave = t >> 6, lane = t & 63;
    int lrow = lane & 15, lq = lane >> 4;

    f32x4 zero4 = {0.f, 0.f, 0.f, 0.f};
    f32x4 acc[2][4];
#pragma unroll
    for (int i = 0; i < 2; i++)
#pragma unroll
        for (int n = 0; n < 4; n++) acc[i][n] = zero4;

    int arow = t >> 1, ahalf = (t & 1) * 16;
    int brow = t >> 2, bq = (t & 3) * 8;

    for (int k0 = 0; k0 < KP; k0 += 32) {
        size_t abase = (size_t)(p0 + arow) * KP + k0 + ahalf;
        size_t bbase = (size_t)(l0 + brow) * KP + k0 + bq;
        uint4 ah0 = *(const uint4*)&Ah[abase];
        uint4 ah1 = *(const uint4*)&Ah[abase + 8];
        uint4 al0 = *(const uint4*)&Al[abase];
        uint4 al1 = *(const uint4*)&Al[abase + 8];
        uint4 bh0 = *(const uint4*)&Bh[bbase];
        uint4 bl0 = *(const uint4*)&Bl[bbase];
        __syncthreads();
        *(uint4*)&AhS[arow][ahalf] = ah0;
        *(uint4*)&AhS[arow][ahalf + 8] = ah1;
        *(uint4*)&AlS[arow][ahalf] = al0;
        *(uint4*)&AlS[arow][ahalf + 8] = al1;
        *(uint4*)&BhS[brow][bq] = bh0;
        *(uint4*)&BlS[brow][bq] = bl0;
        __syncthreads();

        bf16x8 ah[2], al[2], bh[4], blo[4];
#pragma unroll
        for (int i = 0; i < 2; i++) {
            ah[i] = *(const bf16x8*)&AhS[wave * 32 + i * 16 + lrow][lq * 8];
            al[i] = *(const bf16x8*)&AlS[wave * 32 + i * 16 + lrow][lq * 8];
        }
#pragma unroll
        for (int n = 0; n < 4; n++) {
            bh[n] = *(const bf16x8*)&BhS[n * 16 + lrow][lq * 8];
            blo[n] = *(const bf16x8*)&BlS[n * 16 + lrow][lq * 8];
        }
#pragma unroll
        for (int i = 0; i < 2; i++)
#pragma unroll
            for (int n = 0; n < 4; n++) {
                acc[i][n] = __builtin_amdgcn_mfma_f32_16x16x32_bf16(ah[i], bh[n], acc[i][n], 0, 0, 0);
                acc[i][n] = __builtin_amdgcn_mfma_f32_16x16x32_bf16(ah[i], blo[n], acc[i][n], 0, 0, 0);
                acc[i][n] = __builtin_amdgcn_mfma_f32_16x16x32_bf16(al[i], bh[n], acc[i][n], 0, 0, 0);
            }
    }

#pragma unroll
    for (int i = 0; i < 2; i++)
#pragma unroll
        for (int n = 0; n < 4; n++) {
            int row = p0 + wave * 32 + i * 16 + lq * 4;
            int col = l0 + n * 16 + lrow;
            float mmc = mmv[col];
#pragma unroll
            for (int r = 0; r < 4; r++) {
                float z = (mmc > 0.f) ? 10.0f * acc[i][n][r] : 0.f;
                Z[(size_t)(row + r) * LP + col] = z;
            }
        }
}

// ---------------------------------------------------------------------------
// statsW: softmax stats per row, then W[p,l] = bf16(exp(z-m)/denom * mm[l])
// in-place over the Z row prefix.
// ---------------------------------------------------------------------------
__global__ __launch_bounds__(256) void statsW_kernel(
    float* __restrict__ Z, const float* __restrict__ mmv)
{
    int p = blockIdx.x;
    int t = threadIdx.x;
    float4* Z4 = (float4*)(Z + (size_t)p * LP);
    __shared__ float red[256];

    float4 z[4];
    float mx = -1e30f;
#pragma unroll
    for (int i = 0; i < 4; i++) {
        z[i] = Z4[t + 256 * i];
        mx = fmaxf(mx, fmaxf(fmaxf(z[i].x, z[i].y), fmaxf(z[i].z, z[i].w)));
    }
    red[t] = mx;
    __syncthreads();
    for (int s = 128; s > 0; s >>= 1) {
        if (t < s) red[t] = fmaxf(red[t], red[t + s]);
        __syncthreads();
    }
    float m = red[0];
    __syncthreads();

    float4 e[4];
    float sum = 0.f;
#pragma unroll
    for (int i = 0; i < 4; i++) {
        e[i].x = expf(z[i].x - m);
        e[i].y = expf(z[i].y - m);
        e[i].z = expf(z[i].z - m);
        e[i].w = expf(z[i].w - m);
        sum += e[i].x + e[i].y + e[i].z + e[i].w;
    }
    red[t] = sum;
    __syncthreads();
    for (int s = 128; s > 0; s >>= 1) {
        if (t < s) red[t] += red[t + s];
        __syncthreads();
    }
    float dinv = 1.0f / red[0];

    const float4* mm4 = (const float4*)mmv;
    uint2* W2 = (uint2*)(Z + (size_t)p * LP);
#pragma unroll
    for (int i = 0; i < 4; i++) {
        float4 mm = mm4[t + 256 * i];
        uint2 pk;
        pk.x = (unsigned)pack_rne(e[i].x * dinv * mm.x) |
               ((unsigned)pack_rne(e[i].y * dinv * mm.y) << 16);
        pk.y = (unsigned)pack_rne(e[i].z * dinv * mm.z) |
               ((unsigned)pack_rne(e[i].w * dinv * mm.w) << 16);
        W2[t + 256 * i] = pk;
    }
}

// ---------------------------------------------------------------------------
// gemmU via bf16 MFMA, tile 64p x 256c (ALL cols per block -> W read once),
// split-K=8 with fp32 atomics. Grid (64 p-tiles, 8 kz).
// LDS: Ws 64x40 (5 KB) + Vs 256x40 (20 KB).
// ---------------------------------------------------------------------------
__global__ __launch_bounds__(256) void gemmU_mfma_kernel(
    const unsigned short* __restrict__ W16,   // [4096][stride 8192]
    const unsigned short* __restrict__ VT,    // [256][4096]
    float* __restrict__ U)                    // [4096][256]
{
    __shared__ unsigned short Ws[64][40];
    __shared__ unsigned short Vs[256][40];

    int t = threadIdx.x;
    int p0 = blockIdx.x * 64;
    int kz = blockIdx.y;

    int wave = t >> 6, lane = t & 63;
    int lrow = lane & 15, lq = lane >> 4;

    f32x4 zero4 = {0.f, 0.f, 0.f, 0.f};
    f32x4 acc[16];
#pragma unroll
    for (int n = 0; n < 16; n++) acc[n] = zero4;

    int wrow = t >> 2, wq = (t & 3) * 8;   // W loader: 64 rows x 4 k-octets
    int vq = (t & 3) * 8;

    for (int l0 = kz * 512; l0 < kz * 512 + 512; l0 += 32) {
        uint4 w0 = *(const uint4*)&W16[(size_t)(p0 + wrow) * 8192 + l0 + wq];
        uint4 v0 = *(const uint4*)&VT[(size_t)((t >> 2) + 0)   * LP + l0 + vq];
        uint4 v1 = *(const uint4*)&VT[(size_t)((t >> 2) + 64)  * LP + l0 + vq];
        uint4 v2 = *(const uint4*)&VT[(size_t)((t >> 2) + 128) * LP + l0 + vq];
        uint4 v3 = *(const uint4*)&VT[(size_t)((t >> 2) + 192) * LP + l0 + vq];
        __syncthreads();
        *(uint4*)&Ws[wrow][wq] = w0;
        *(uint4*)&Vs[(t >> 2) + 0][vq] = v0;
        *(uint4*)&Vs[(t >> 2) + 64][vq] = v1;
        *(uint4*)&Vs[(t >> 2) + 128][vq] = v2;
        *(uint4*)&Vs[(t >> 2) + 192][vq] = v3;
        __syncthreads();

        bf16x8 a = *(const bf16x8*)&Ws[wave * 16 + lrow][lq * 8];
#pragma unroll
        for (int n = 0; n < 16; n++) {
            bf16x8 b = *(const bf16x8*)&Vs[n * 16 + lrow][lq * 8];
            acc[n] = __builtin_amdgcn_mfma_f32_16x16x32_bf16(a, b, acc[n], 0, 0, 0);
        }
    }

#pragma unroll
    for (int n = 0; n < 16; n++) {
        int row = p0 + wave * 16 + lq * 4;
        int col = n * 16 + lrow;
#pragma unroll
        for (int r = 0; r < 4; r++)
            atomicAdd(&U[(size_t)(row + r) * N2 + col], acc[n][r]);
    }
}

// ---------------------------------------------------------------------------
// gather / overlap-add (upright), fp32 out
// ---------------------------------------------------------------------------
__global__ __launch_bounds__(256) void gather_kernel(
    const float* __restrict__ U, float* __restrict__ out)
{
    int idx = blockIdx.x * 256 + threadIdx.x;
    int ox = idx & 127;
    int t1 = idx >> 7;
    int oy = t1 & 127;
    int t2 = t1 >> 7;
    int c = t2 & 15;
    int b = t2 >> 4;

    float sum = 0.f;
    int d0y = (oy + 1) & 1, d0x = (ox + 1) & 1;
#pragma unroll
    for (int iy = 0; iy < 2; iy++) {
        int dy = d0y + 2 * iy;
        int y = (oy + 1 - dy) >> 1;
        if (y < 0 || y > 63) continue;
#pragma unroll
        for (int ix = 0; ix < 2; ix++) {
            int dx = d0x + 2 * ix;
            int x = (ox + 1 - dx) >> 1;
            if (x < 0 || x > 63) continue;
            sum += U[((long)b * LP + y * 64 + x) * N2 + c * 16 + dy * 4 + dx];
        }
    }
    out[idx] = sum * 0.25f;
}

// ---------------------------------------------------------------------------
extern "C" void kernel_launch(void* const* d_in, const int* in_sizes, int n_in,
                              void* d_out, int out_size, void* d_ws, size_t ws_size,
                              hipStream_t stream)
{
    const void* fg   = d_in[0];
    const void* bg   = d_in[1];
    const void* mask = d_in[2];
    float* out = (float*)d_out;

    char* w = (char*)d_ws;
    size_t o = 0;
    int*            flag = (int*)(w + o);            o += 16;
    unsigned short* Fh   = (unsigned short*)(w + o); o += (size_t)BB * LP * KP * 2;
    unsigned short* Fl   = (unsigned short*)(w + o); o += (size_t)BB * LP * KP * 2;
    unsigned short* Kh   = (unsigned short*)(w + o); o += (size_t)BB * LP * KP * 2;
    unsigned short* Kl   = (unsigned short*)(w + o); o += (size_t)BB * LP * KP * 2;
    unsigned short* VT   = (unsigned short*)(w + o); o += (size_t)BB * N2 * LP * 2;
    float*          U    = (float*)(w + o);          o += (size_t)BB * LP * N2 * 4;
    float*          mmg  = (float*)(w + o);          o += (size_t)BB * LP * 4;
    float*          Z    = (float*)(w + o);          o += (size_t)LP * LP * 4;

    detect_kernel<<<1, 64, 0, stream>>>((const unsigned int*)fg, flag);
    prep_kernel<<<BB * LP, 256, 0, stream>>>(fg, bg, mask, flag, Fh, Fl, Kh, Kl, mmg);
    vT_kernel<<<dim3(LP / 16, BB), 256, 0, stream>>>(bg, flag, VT);
    zeroU_kernel<<<(BB * LP * N2 / 4) / 256, 256, 0, stream>>>((float4*)U);

    for (int b = 0; b < BB; b++) {
        gemmZ_mfma_kernel<<<dim3(64, 32), 256, 0, stream>>>(
            Fh + (size_t)b * LP * KP, Fl + (size_t)b * LP * KP,
            Kh + (size_t)b * LP * KP, Kl + (size_t)b * LP * KP,
            mmg + (size_t)b * LP, Z);
        statsW_kernel<<<LP, 256, 0, stream>>>(Z, mmg + (size_t)b * LP);
        gemmU_mfma_kernel<<<dim3(64, 8), 256, 0, stream>>>(
            (const unsigned short*)Z, VT + (size_t)b * N2 * LP,
            U + (size_t)b * LP * N2);
    }

    gather_kernel<<<(BB * CC * HH * WW) / 256, 256, 0, stream>>>(U, out);
}